// Round 5
// baseline (303.492 us; speedup 1.0000x reference)
//
#include <hip/hip_runtime.h>
#include <hip/hip_bf16.h>

#define HW 65536
#define WST 29952   // per-sample fp32 effective-weight stride (floats)

typedef unsigned short U16;
typedef __attribute__((ext_vector_type(8))) short short8;
typedef __attribute__((ext_vector_type(4))) unsigned short us4;
typedef __attribute__((ext_vector_type(4))) float float4v;

// ws byte offsets
#define WEFF_OFF 0
#define FRAG_OFF 524288        // U16[4][24576]: w1f@0, w3f@8192, w4f@12288, w5f@20480
#define POOL_OFF 786432        // float[256]
#define SCA_OFF  787456        // float[256] (unused; sca folded into k_stage2)
#define Z_OFF    68157440      // U16[4][64][HW]

__device__ inline U16 f2bf(float f) {
  union { float f; unsigned u; } v; v.f = f;
  unsigned r = v.u + 0x7FFF + ((v.u >> 16) & 1);   // RNE
  return (U16)(r >> 16);
}
// packed RNE pair conversion via HIP intrinsic (compiler lowers to packed cvt;
// numerically identical RNE to f2bf). low 16 bits = a, high = b.
__device__ inline unsigned pack2(float a, float b) {
  union { __hip_bfloat162 h; unsigned u; } v;
  v.h = __float22bfloat162_rn(float2{a, b});
  return v.u;
}
__device__ inline float bf2f(U16 h) {
  union { unsigned u; float f; } v; v.u = ((unsigned)h) << 16;
  return v.f;
}
__device__ inline float asfhi(unsigned u) {   // high bf16 of dword
  union { unsigned u; float f; } v; v.u = u & 0xffff0000u; return v.f;
}
__device__ inline float asflo(unsigned u) {   // low bf16 of dword
  union { unsigned u; float f; } v; v.u = u << 16; return v.f;
}

// ---------------- kernel 1: per-sample effective weights + bf16 MFMA B-fragments ----
// 24 blocks = 4 samples x 6 sections. Also computes S[n]=sum_c w1g (w1g = w1e*ln1w,
// bf16-rounded to match fragments) and Bn[n]=b1+sum_c w1e*ln1b for the LN-folded conv1.
__global__ __launch_bounds__(256) void k_weights(const float* __restrict__ probs,
    const float* __restrict__ w1, const float* __restrict__ la1, const float* __restrict__ lb1,
    const float* __restrict__ w2, const float* __restrict__ la2, const float* __restrict__ lb2,
    const float* __restrict__ wsca, const float* __restrict__ lasca, const float* __restrict__ lbsca,
    const float* __restrict__ w3, const float* __restrict__ la3, const float* __restrict__ lb3,
    const float* __restrict__ w4, const float* __restrict__ la4, const float* __restrict__ lb4,
    const float* __restrict__ w5, const float* __restrict__ la5, const float* __restrict__ lb5,
    const float* __restrict__ b3, const float* __restrict__ b5,
    const float* __restrict__ beta, const float* __restrict__ gamma,
    const float* __restrict__ ln1w, const float* __restrict__ ln1b, const float* __restrict__ b1,
    float* __restrict__ weff, U16* __restrict__ fragw)
{
  __shared__ float sb[5952];
  int blk = blockIdx.x;
  int b = blk / 6, sec = blk - b * 6;
  int tid = threadIdx.x;
  float p0 = probs[b*3+0], p1 = probs[b*3+1], p2 = probs[b*3+2];
  int e = 0; float g = p0;
  if (p1 > g) { g = p1; e = 1; }
  if (p2 > g) { g = p2; e = 2; }
  float s = 2.0f * g;               // SCALING * gate
  float* wfp = weff + b * WST;
  U16* fws = fragw + b * 24576;

  if (sec == 1) {
    // ---- w2e (depthwise 3x3, 1152) + folded biases + S/Bn for conv1 LN-fold ----
    const float* lbs = lb2 + e * 4608;
    const float* las = la2 + e * 36;
    for (int i = tid; i < 4608; i += 256) sb[i] = lbs[i];
    if (tid < 36) sb[4608 + tid] = las[tid];
    if (tid < 64) {
      sb[4644 + tid] = b3[tid];  sb[4708 + tid] = b5[tid];
      sb[4772 + tid] = beta[tid]; sb[4836 + tid] = gamma[tid];
      sb[5668 + tid] = ln1w[tid]; sb[5732 + tid] = ln1b[tid];
    }
    if (tid < 256) sb[4900 + tid] = la1[e*256 + tid];
    for (int i = tid; i < 512; i += 256) sb[5156 + i] = lb1[e*512 + i];
    if (tid < 128) sb[5796 + tid] = b1[tid];
    __syncthreads();
    for (int idx = tid; idx < 1152; idx += 256) {
      int row = idx / 3, dx = idx - row * 3;
      float acc = w2[idx];
      #pragma unroll
      for (int r = 0; r < 12; ++r)
        acc += s * sb[row*12 + r] * sb[4608 + r*3 + dx];
      wfp[8192 + idx] = acc;
    }
    if (tid < 64) {
      wfp[29824 + tid] = sb[4644 + tid] * sb[4772 + tid];   // b3 * beta
      wfp[29888 + tid] = sb[4708 + tid] * sb[4836 + tid];   // b5 * gamma
    }
    if (tid >= 128) {
      int n = tid - 128;
      float S = 0.f, Bn = sb[5796 + n];
      for (int c = 0; c < 64; ++c) {
        float wv = w1[n*64 + c];
        #pragma unroll
        for (int r = 0; r < 4; ++r) wv += s * sb[5156 + n*4 + r] * sb[4900 + r*64 + c];
        S  += bf2f(f2bf(wv * sb[5668 + c]));    // match fragment rounding
        Bn += wv * sb[5732 + c];
      }
      wfp[n] = S; wfp[128 + n] = Bn;
    }
    return;
  }
  if (sec == 2) {
    // ---- wscat [c][k] @9344 (4096) ----
    const float* lbs = lbsca + e * 256;
    const float* las = lasca + e * 256;
    if (tid < 256) { sb[tid] = lbs[tid]; sb[256 + tid] = las[tid]; }
    __syncthreads();
    #pragma unroll 4
    for (int idx = tid; idx < 4096; idx += 256) {
      int c = idx >> 6, k = idx & 63;
      float acc = wsca[k*64 + c];
      #pragma unroll
      for (int r = 0; r < 4; ++r)
        acc += s * sb[k*4 + r] * sb[256 + r*64 + c];
      wfp[9344 + idx] = acc;
    }
    return;
  }

  // ---- fragment sections: value = (w[n*64+k] + s*lb[n][:]@la[:][k]) * scale ----
  const float *w, *la, *lb, *scl = nullptr;
  bool sclk = false;
  int fo, cnt;
  if (sec == 0)      { w = w1; lb = lb1 + e*512; la = la1 + e*256; fo = 0;     cnt = 8192; scl = ln1w; sclk = true; }
  else if (sec == 3) { w = w3; lb = lb3 + e*256; la = la3 + e*256; fo = 8192;  cnt = 4096; scl = beta; }
  else if (sec == 4) { w = w4; lb = lb4 + e*512; la = la4 + e*256; fo = 12288; cnt = 8192; }
  else               { w = w5; lb = lb5 + e*256; la = la5 + e*256; fo = 20480; cnt = 4096; scl = gamma; }
  int nlb = (cnt == 8192) ? 512 : 256;
  for (int i = tid; i < nlb; i += 256) sb[i] = lb[i];
  if (tid < 256) sb[512 + tid] = la[tid];
  if (scl && tid < 64) sb[768 + tid] = scl[tid];
  __syncthreads();
  #pragma unroll 4
  for (int idx = tid; idx < cnt; idx += 256) {
    int j = idx & 7, l = (idx >> 3) & 63, s2 = (idx >> 9) & 1, nt = idx >> 10;
    int n = nt*16 + (l & 15), k = s2*32 + ((l >> 4) << 3) + j;
    float acc = w[n*64 + k];
    #pragma unroll
    for (int r = 0; r < 4; ++r)
      acc += s * sb[n*4 + r] * sb[512 + r*64 + k];
    if (scl) acc *= sb[768 + (sclk ? k : n)];
    fws[fo + idx] = f2bf(acc);
  }
}

// ---------------- kernel 2 (fused): LN1 + conv1 (MFMA) + dw3x3 + SimpleGate + pool ----
// block = (b, group, 8x32 tile). t1 never leaves LDS. Group g computes gated
// channels g*32..g*32+31 (t1 channels g*32+i and 64+g*32+i). 2048 blocks.
#define MTS 22   // m-tiles for 340 halo px
__global__ __launch_bounds__(256, 3) void k_stage1f(
    const float* __restrict__ inp, const float* __restrict__ b2,
    const float* __restrict__ weff, const U16* __restrict__ fragw,
    U16* __restrict__ z, float* __restrict__ pooled)
{
  __shared__ __align__(16) U16 smu[22528];   // union: afrag (22*1024) / t1s (64*348) / pool scratch
  __shared__ float2 muinv[344];
  int blk = blockIdx.x;
  int tile = blk & 255;
  int g = (blk >> 8) & 1;
  int b = blk >> 9;
  int h0 = (tile >> 3) * 8, w0 = (tile & 7) * 32;
  int tid = threadIdx.x, lane = tid & 63, w = tid >> 6;
  const float* wfp = weff + b * WST;
  const U16* fw = fragw + b * 24576;

  // ---- P1: raw inp -> mu/inv + bf16 A-frags (no normalize; LN folded in epilogue) ----
  for (int it = 0; it < 2; ++it) {
    int i = tid + it * 256;
    if (i >= 340) break;
    int hy = i / 34, hx = i - hy * 34;
    int h = h0 - 1 + hy, ww = w0 - 1 + hx;
    int mt = i >> 4, m = i & 15;
    if (h >= 0 && h < 256 && ww >= 0 && ww < 256) {
      const float* src = inp + (size_t)b * 64 * HW + h * 256 + ww;
      float x[64];
      #pragma unroll
      for (int c = 0; c < 64; ++c) x[c] = src[(size_t)c * HW];
      float s0=0,s1=0,q0=0,q1=0;
      #pragma unroll
      for (int c = 0; c < 64; c += 2) {
        s0 += x[c];   q0 += x[c]*x[c];
        s1 += x[c+1]; q1 += x[c+1]*x[c+1];
      }
      float mu  = (s0+s1) * (1.f/64.f);
      float inv = rsqrtf(fmaxf((q0+q1)*(1.f/64.f) - mu*mu, 0.f) + 1e-6f);
      muinv[i] = float2{mu, inv};
      #pragma unroll
      for (int s = 0; s < 2; ++s)
        #pragma unroll
        for (int q = 0; q < 4; ++q) {
          union { unsigned u[4]; short8 v; } pk;
          #pragma unroll
          for (int j = 0; j < 4; ++j)
            pk.u[j] = pack2(x[s*32 + q*8 + 2*j], x[s*32 + q*8 + 2*j + 1]);
          *(short8*)&smu[mt*1024 + s*512 + (q*16 + m)*8] = pk.v;
        }
    } else {
      muinv[i] = float2{0.f, 0.f};   // inv==0 flags "outside image" -> t1 = 0
    }
  }

  // B-frags + S/Bn for this group's 4 n-tiles (done pre-barrier; independent of LDS)
  int n15 = lane & 15;
  short8 bw[8];
  float Sr[4], Br[4];
  #pragma unroll
  for (int ntl = 0; ntl < 4; ++ntl) {
    int ntg = (ntl < 2) ? (g*2 + ntl) : (4 + g*2 + (ntl - 2));
    #pragma unroll
    for (int s = 0; s < 2; ++s)
      bw[ntl*2 + s] = *(const short8*)&fw[((ntg*2 + s)*64 + lane)*8];
    int ng = ntg*16 + n15;
    Sr[ntl] = wfp[ng];
    Br[ntl] = wfp[128 + ng];
  }
  __syncthreads();

  // ---- P2: MFMA (raw-x conv1 with pre-scaled weights) ----
  int mt0 = w * 6;
  int nmt = MTS - mt0; if (nmt > 6) nmt = 6;   // 6,6,6,4
  float4v acc[6][4];
  #pragma unroll
  for (int mi = 0; mi < 6; ++mi)
    #pragma unroll
    for (int ntl = 0; ntl < 4; ++ntl) acc[mi][ntl] = (float4v)(0.f);
  #pragma unroll
  for (int mi = 0; mi < 6; ++mi) {
    if (mi < nmt) {
      int mt = mt0 + mi;
      #pragma unroll
      for (int s = 0; s < 2; ++s) {
        short8 a = *(const short8*)&smu[mt*1024 + s*512 + lane*8];
        #pragma unroll
        for (int ntl = 0; ntl < 4; ++ntl)
          acc[mi][ntl] = __builtin_amdgcn_mfma_f32_16x16x32_bf16(a, bw[ntl*2 + s], acc[mi][ntl], 0, 0, 0);
      }
    }
  }
  __syncthreads();   // afrag dead; smu becomes t1s[64][348]

  // ---- P3: epilogue t1 = inv*(A - mu*S) + Bn (0 outside image) -> t1s ----
  int q = lane >> 4;
  #pragma unroll
  for (int mi = 0; mi < 6; ++mi) {
    if (mi < nmt) {
      int px0 = (mt0 + mi)*16 + q*4;
      if (px0 < 340) {
        float2 m0 = muinv[px0], m1 = muinv[px0+1], m2 = muinv[px0+2], m3 = muinv[px0+3];
        #pragma unroll
        for (int ntl = 0; ntl < 4; ++ntl) {
          float S = Sr[ntl], B = Br[ntl];
          float v0 = m0.y*(acc[mi][ntl][0] - m0.x*S) + B;
          float v1 = m1.y*(acc[mi][ntl][1] - m1.x*S) + B;
          float v2 = m2.y*(acc[mi][ntl][2] - m2.x*S) + B;
          float v3 = m3.y*(acc[mi][ntl][3] - m3.x*S) + B;
          v0 = m0.y > 0.f ? v0 : 0.f;
          v1 = m1.y > 0.f ? v1 : 0.f;
          v2 = m2.y > 0.f ? v2 : 0.f;
          v3 = m3.y > 0.f ? v3 : 0.f;
          union { unsigned u[2]; us4 v; } pk;
          pk.u[0] = pack2(v0, v1);
          pk.u[1] = pack2(v2, v3);
          *(us4*)&smu[(ntl*16 + n15)*348 + px0] = pk.v;
        }
      }
    }
  }
  __syncthreads();

  // ---- P4: depthwise 3x3 + gate + z write; pool deferred to registers ----
  // thread = (channel half, 2-px pair). taps for even pair = 2 aligned dwords/row.
  // Fully unrolled so psum[] stays in registers (runtime-indexed arrays spill)
  // and kl-dependent LDS addresses const-fold.
  float psum[16];
  {
    int half = tid >> 7;               // wave-uniform
    int pp = (tid & 127) * 2;
    int cy = pp >> 5, cx = pp & 31;
    const float* w2e = wfp + 8192;
    U16* zb = z + (size_t)b*64*HW + (size_t)(h0 + cy)*256 + (w0 + cx);
    #pragma unroll
    for (int i = 0; i < 16; ++i) {
      int kl = half*16 + i;
      int kg = g*32 + kl;
      unsigned ua[3][2], uc[3][2];
      #pragma unroll
      for (int dy = 0; dy < 3; ++dy) {
        int basea = kl*348 + (cy + dy)*34 + cx;
        int basec = (32 + kl)*348 + (cy + dy)*34 + cx;
        ua[dy][0] = *(unsigned*)&smu[basea]; ua[dy][1] = *(unsigned*)&smu[basea + 2];
        uc[dy][0] = *(unsigned*)&smu[basec]; uc[dy][1] = *(unsigned*)&smu[basec + 2];
      }
      const float* wa = w2e + kg*9;
      const float* wc = w2e + (kg + 64)*9;
      float a0 = b2[kg], a1 = a0;
      float c0 = b2[kg + 64], c1 = c0;
      #pragma unroll
      for (int dy = 0; dy < 3; ++dy) {
        float x0 = asflo(ua[dy][0]), x1 = asfhi(ua[dy][0]), x2 = asflo(ua[dy][1]), x3 = asfhi(ua[dy][1]);
        a0 += wa[dy*3]*x0 + wa[dy*3+1]*x1 + wa[dy*3+2]*x2;
        a1 += wa[dy*3]*x1 + wa[dy*3+1]*x2 + wa[dy*3+2]*x3;
        x0 = asflo(uc[dy][0]); x1 = asfhi(uc[dy][0]); x2 = asflo(uc[dy][1]); x3 = asfhi(uc[dy][1]);
        c0 += wc[dy*3]*x0 + wc[dy*3+1]*x1 + wc[dy*3+2]*x2;
        c1 += wc[dy*3]*x1 + wc[dy*3+1]*x2 + wc[dy*3+2]*x3;
      }
      float z0 = a0*c0, z1 = a1*c1;
      *(unsigned*)(zb + (size_t)kg * HW) = pack2(z0, z1);
      psum[i] = z0 + z1;
    }
  }
  // ---- pool reduction: dump psum to (dead) t1s LDS, cooperative reduce ----
  __syncthreads();                       // all t1s reads finished
  {
    float* fs = (float*)smu;             // [256][17] floats = 17408 B < 45056
    #pragma unroll
    for (int i = 0; i < 16; ++i) fs[tid*17 + i] = psum[i];
    __syncthreads();
    int ch = tid >> 3, sub = tid & 7;    // ch 0..31, 8 reducers each
    int hf = ch >> 4, ii = ch & 15;
    float v = 0.f;
    #pragma unroll
    for (int j = 0; j < 16; ++j)
      v += fs[(hf*128 + sub*16 + j)*17 + ii];
    v += __shfl_down(v, 4, 64);
    v += __shfl_down(v, 2, 64);
    v += __shfl_down(v, 1, 64);
    if (sub == 0) atomicAdd(&pooled[b*64 + g*32 + ch], v);
  }
}

// ---------------- kernel 3 (fused into top): sca + xsca -> conv3 -> +inp (beta folded)
// -> LN2 -> conv4 -> gate -> conv5.  block = (b, h): one image row.
__global__ __launch_bounds__(256, 2) void k_stage2(
    const float* __restrict__ inp, const U16* __restrict__ z,
    const float* __restrict__ bsca, const float* __restrict__ pooled,
    const float* __restrict__ ln2w, const float* __restrict__ ln2b, const float* __restrict__ b4,
    const float* __restrict__ weff, const U16* __restrict__ fragw, float* __restrict__ out)
{
  __shared__ __align__(16) U16 yb[256*72];      // y, bf16, stride 72
  __shared__ __align__(16) char afr[34816];     // afrag U16[16384] / afragF float[256*33]
  __shared__ float spart[256];
  __shared__ float ssca[64];
  U16* afrag = (U16*)afr;
  float* afragF = (float*)afr;
  int blk = blockIdx.x;
  int b = blk >> 8, h = blk & 255;
  int tid = threadIdx.x, lane = tid & 63, w = tid >> 6;
  const float* wb = weff + b * WST;
  const U16* fw = fragw + b * 24576;

  { // phase 0: sca[b][k] = bsca[k] + sum_c wscat[c][k] * mean(pool) (was k_sca)
    int k = tid & 63, qq = tid >> 6;
    const float* wt = wb + 9344;               // wscat [c][k]
    const float* pm = pooled + b * 64;
    float part = 0.f;
    #pragma unroll
    for (int j = 0; j < 16; ++j) {
      int c = qq * 16 + j;
      part += wt[c * 64 + k] * (pm[c] * (1.f/65536.f));
    }
    spart[tid] = part;
  }
  __syncthreads();
  if (tid < 64)
    ssca[tid] = bsca[tid] + spart[tid] + spart[64 + tid] + spart[128 + tid] + spart[192 + tid];
  __syncthreads();

  float y0[64];
  { // phase A: xs = z*sca -> A-frags; y0 = inp row
    const U16* zp = z + (size_t)b*64*HW + h*256 + tid;
    float xs[64];
    #pragma unroll
    for (int k = 0; k < 64; ++k) xs[k] = bf2f(zp[(size_t)k * HW]) * ssca[k];
    int mt = tid >> 4, m = tid & 15;
    #pragma unroll
    for (int s = 0; s < 2; ++s)
      #pragma unroll
      for (int q = 0; q < 4; ++q) {
        union { unsigned u[4]; short8 v; } pk;
        #pragma unroll
        for (int j = 0; j < 4; ++j)
          pk.u[j] = pack2(xs[s*32 + q*8 + 2*j], xs[s*32 + q*8 + 2*j + 1]);
        *(short8*)&afrag[mt*1024 + s*512 + (q*16 + m)*8] = pk.v;
      }
    const float* ip = inp + (size_t)b*64*HW + h*256 + tid;
    #pragma unroll
    for (int c = 0; c < 64; ++c) y0[c] = ip[(size_t)c * HW];
  }
  __syncthreads();

  { // conv3: [256x64] @ w3bt[64x64] -> yb (bf16, pre-residual)
    short8 bw3[8];
    #pragma unroll
    for (int i = 0; i < 8; ++i) bw3[i] = *(const short8*)&fw[8192 + (i*64 + lane)*8];
    float4v acc[4][4];
    #pragma unroll
    for (int mi = 0; mi < 4; ++mi)
      #pragma unroll
      for (int nt = 0; nt < 4; ++nt) acc[mi][nt] = (float4v)(0.f);
    #pragma unroll
    for (int mi = 0; mi < 4; ++mi) {
      int mt = w*4 + mi;
      #pragma unroll
      for (int s = 0; s < 2; ++s) {
        short8 a = *(const short8*)&afrag[mt*1024 + s*512 + lane*8];
        #pragma unroll
        for (int nt = 0; nt < 4; ++nt)
          acc[mi][nt] = __builtin_amdgcn_mfma_f32_16x16x32_bf16(a, bw3[nt*2 + s], acc[mi][nt], 0, 0, 0);
      }
    }
    #pragma unroll
    for (int mi = 0; mi < 4; ++mi) {
      int pxb = (w*4 + mi)*16 + ((lane >> 4) << 2);
      #pragma unroll
      for (int nt = 0; nt < 4; ++nt) {
        int c = nt*16 + (lane & 15);
        #pragma unroll
        for (int r = 0; r < 4; ++r)
          yb[(pxb + r)*72 + c] = f2bf(acc[mi][nt][r]);
      }
    }
  }
  __syncthreads();

  { // phase C (thread = pixel): residual + LN2 -> xln A-frags; write y back (bf16)
    const float* b3b = wb + 29824;
    float y[64];
    #pragma unroll
    for (int c8 = 0; c8 < 8; ++c8) {
      short8 v = *(const short8*)&yb[tid*72 + c8*8];
      #pragma unroll
      for (int j = 0; j < 8; ++j) y[c8*8 + j] = bf2f((U16)v[j]);
    }
    #pragma unroll
    for (int c = 0; c < 64; ++c) y[c] += y0[c] + b3b[c];
    float s0=0,s1=0,q0=0,q1=0;
    #pragma unroll
    for (int c = 0; c < 64; c += 2) {
      s0 += y[c];   q0 += y[c]*y[c];
      s1 += y[c+1]; q1 += y[c+1]*y[c+1];
    }
    float mu  = (s0+s1) * (1.f/64.f);
    float inv = rsqrtf((q0+q1) * (1.f/64.f) - mu*mu + 1e-6f);
    int mt = tid >> 4, m = tid & 15;
    #pragma unroll
    for (int s = 0; s < 2; ++s)
      #pragma unroll
      for (int q = 0; q < 4; ++q) {
        union { unsigned u[4]; short8 v; } pk;
        #pragma unroll
        for (int j = 0; j < 4; ++j) {
          int c = s*32 + q*8 + 2*j;
          float e0 = (y[c]   - mu) * inv * ln2w[c]   + ln2b[c];
          float e1 = (y[c+1] - mu) * inv * ln2w[c+1] + ln2b[c+1];
          pk.u[j] = pack2(e0, e1);
        }
        *(short8*)&afrag[mt*1024 + s*512 + (q*16 + m)*8] = pk.v;
      }
    #pragma unroll
    for (int c8 = 0; c8 < 8; ++c8) {
      union { unsigned u[4]; short8 v; } pk;
      #pragma unroll
      for (int j = 0; j < 4; ++j)
        pk.u[j] = pack2(y[c8*8 + 2*j], y[c8*8 + 2*j + 1]);
      *(short8*)&yb[tid*72 + c8*8] = pk.v;
    }
  }
  __syncthreads();

  float4v acc5[4][4];
  { // conv4 (64->128) + in-register SimpleGate -> g A-frags (own-wave region) -> conv5
    short8 bw4[16];
    #pragma unroll
    for (int i = 0; i < 16; ++i) bw4[i] = *(const short8*)&fw[12288 + (i*64 + lane)*8];
    float b4a[8];
    #pragma unroll
    for (int nt = 0; nt < 8; ++nt) b4a[nt] = b4[nt*16 + (lane & 15)];
    float4v acc[4][8];
    #pragma unroll
    for (int mi = 0; mi < 4; ++mi)
      #pragma unroll
      for (int nt = 0; nt < 8; ++nt) acc[mi][nt] = (float4v)(0.f);
    #pragma unroll
    for (int mi = 0; mi < 4; ++mi) {
      int mt = w*4 + mi;
      #pragma unroll
      for (int s = 0; s < 2; ++s) {
        short8 a = *(const short8*)&afrag[mt*1024 + s*512 + lane*8];
        #pragma unroll
        for (int nt = 0; nt < 8; ++nt)
          acc[mi][nt] = __builtin_amdgcn_mfma_f32_16x16x32_bf16(a, bw4[nt*2 + s], acc[mi][nt], 0, 0, 0);
      }
    }
    // gate: t4[px][k] * t4[px][k+64] — same lane, same reg across nt / nt+4
    #pragma unroll
    for (int mi = 0; mi < 4; ++mi) {
      int mt = w*4 + mi;
      int mloc = ((lane >> 4) << 2);
      #pragma unroll
      for (int nt = 0; nt < 4; ++nt) {
        int k = nt*16 + (lane & 15);
        int s_ = k >> 5, q = (k >> 3) & 3, j = k & 7;
        #pragma unroll
        for (int r = 0; r < 4; ++r) {
          float gv = (acc[mi][nt][r] + b4a[nt]) * (acc[mi][nt+4][r] + b4a[nt+4]);
          afrag[mt*1024 + s_*512 + (q*16 + mloc + r)*8 + j] = f2bf(gv);
        }
      }
    }
    // conv5 reads only own-wave region (RAW within wave: no barrier needed)
    short8 bw5[8];
    #pragma unroll
    for (int i = 0; i < 8; ++i) bw5[i] = *(const short8*)&fw[20480 + (i*64 + lane)*8];
    #pragma unroll
    for (int mi = 0; mi < 4; ++mi)
      #pragma unroll
      for (int nt = 0; nt < 4; ++nt) acc5[mi][nt] = (float4v)(0.f);
    #pragma unroll
    for (int mi = 0; mi < 4; ++mi) {
      int mt = w*4 + mi;
      #pragma unroll
      for (int s = 0; s < 2; ++s) {
        short8 a = *(const short8*)&afrag[mt*1024 + s*512 + lane*8];
        #pragma unroll
        for (int nt = 0; nt < 4; ++nt)
          acc5[mi][nt] = __builtin_amdgcn_mfma_f32_16x16x32_bf16(a, bw5[nt*2 + s], acc5[mi][nt], 0, 0, 0);
      }
    }
  }
  __syncthreads();   // all afrag reads done before fp32 reuse (regions overlap across waves)

  { // epilogue: out = y + b5g + conv5, fp32, coalesced via LDS transpose (own-wave rows)
    const float* b5g = wb + 29888;
    float b5f[4];
    #pragma unroll
    for (int nt = 0; nt < 4; ++nt) b5f[nt] = b5g[nt*16 + (lane & 15)];
    float* op = out + (size_t)b*64*HW + h*256;
    for (int chalf = 0; chalf < 2; ++chalf) {
      #pragma unroll
      for (int mi = 0; mi < 4; ++mi) {
        int pxb = (w*4 + mi)*16 + ((lane >> 4) << 2);
        #pragma unroll
        for (int nt2 = 0; nt2 < 2; ++nt2) {
          int nt = chalf*2 + nt2;
          int c = nt*16 + (lane & 15);
          #pragma unroll
          for (int r = 0; r < 4; ++r) {
            float v = acc5[mi][nt][r] + b5f[nt] + bf2f(yb[(pxb + r)*72 + c]);
            afragF[(pxb + r)*33 + (c - chalf*32)] = v;
          }
        }
      }
      // own-wave rows: thread tid reads row tid (written by its own wave) — no barrier needed
      #pragma unroll 4
      for (int cc = 0; cc < 32; ++cc)
        op[(size_t)(chalf*32 + cc) * HW + tid] = afragF[tid*33 + cc];
    }
  }
}

extern "C" void kernel_launch(void* const* d_in, const int* in_sizes, int n_in,
                              void* d_out, int out_size, void* d_ws, size_t ws_size,
                              hipStream_t stream) {
  const float* inp   = (const float*)d_in[0];
  const float* probs = (const float*)d_in[1];
  const float* ln1w  = (const float*)d_in[2];
  const float* ln1b  = (const float*)d_in[3];
  const float* ln2w  = (const float*)d_in[4];
  const float* ln2b  = (const float*)d_in[5];
  const float* w1    = (const float*)d_in[6];
  const float* b1    = (const float*)d_in[7];
  const float* la1   = (const float*)d_in[8];
  const float* lb1   = (const float*)d_in[9];
  const float* w2    = (const float*)d_in[10];
  const float* b2    = (const float*)d_in[11];
  const float* la2   = (const float*)d_in[12];
  const float* lb2   = (const float*)d_in[13];
  const float* wsca  = (const float*)d_in[14];
  const float* bsca  = (const float*)d_in[15];
  const float* lasca = (const float*)d_in[16];
  const float* lbsca = (const float*)d_in[17];
  const float* w3    = (const float*)d_in[18];
  const float* b3    = (const float*)d_in[19];
  const float* la3   = (const float*)d_in[20];
  const float* lb3   = (const float*)d_in[21];
  const float* w4    = (const float*)d_in[22];
  const float* b4    = (const float*)d_in[23];
  const float* la4   = (const float*)d_in[24];
  const float* lb4   = (const float*)d_in[25];
  const float* w5    = (const float*)d_in[26];
  const float* b5    = (const float*)d_in[27];
  const float* la5   = (const float*)d_in[28];
  const float* lb5   = (const float*)d_in[29];
  const float* beta  = (const float*)d_in[30];
  const float* gamma = (const float*)d_in[31];

  char* wsb = (char*)d_ws;
  float* weff   = (float*)(wsb + WEFF_OFF);
  U16*   fragw  = (U16*)(wsb + FRAG_OFF);
  float* pooled = (float*)(wsb + POOL_OFF);
  U16*   zws    = (U16*)(wsb + Z_OFF);
  float* outp   = (float*)d_out;

  hipMemsetAsync(pooled, 0, 256 * sizeof(float), stream);
  k_weights<<<dim3(24), dim3(256), 0, stream>>>(probs,
      w1, la1, lb1, w2, la2, lb2, wsca, lasca, lbsca,
      w3, la3, lb3, w4, la4, lb4, w5, la5, lb5,
      b3, b5, beta, gamma, ln1w, ln1b, b1, weff, fragw);
  k_stage1f<<<dim3(2048), dim3(256), 0, stream>>>(inp, b2, weff, fragw, zws, pooled);
  k_stage2<<<dim3(1024), dim3(256), 0, stream>>>(inp, zws, bsca, pooled, ln2w, ln2b, b4, weff, fragw, outp);
}

// Round 6
// 292.237 us; speedup vs baseline: 1.0385x; 1.0385x over previous
//
#include <hip/hip_runtime.h>
#include <hip/hip_bf16.h>

#define HW 65536
#define WST 29952   // per-sample fp32 effective-weight stride (floats)

typedef unsigned short U16;
typedef __attribute__((ext_vector_type(8))) short short8;
typedef __attribute__((ext_vector_type(4))) unsigned short us4;
typedef __attribute__((ext_vector_type(4))) float float4v;

// ws byte offsets
#define WEFF_OFF 0
#define FRAG_OFF 524288        // U16[4][24576]: w1f@0, w3f@8192, w4f@12288, w5f@20480
#define POOL_OFF 786432        // float[256]
#define SCA_OFF  787456        // float[256]
#define Z_OFF    68157440      // U16[4][64][HW]

__device__ inline U16 f2bf(float f) {
  union { float f; unsigned u; } v; v.f = f;
  unsigned r = v.u + 0x7FFF + ((v.u >> 16) & 1);   // RNE
  return (U16)(r >> 16);
}
// packed RNE pair conversion via HIP intrinsic (compiler lowers to packed cvt;
// numerically identical RNE to f2bf). low 16 bits = a, high = b.
__device__ inline unsigned pack2(float a, float b) {
  union { __hip_bfloat162 h; unsigned u; } v;
  v.h = __float22bfloat162_rn(float2{a, b});
  return v.u;
}
__device__ inline float bf2f(U16 h) {
  union { unsigned u; float f; } v; v.u = ((unsigned)h) << 16;
  return v.f;
}
__device__ inline float asfhi(unsigned u) {   // high bf16 of dword
  union { unsigned u; float f; } v; v.u = u & 0xffff0000u; return v.f;
}
__device__ inline float asflo(unsigned u) {   // low bf16 of dword
  union { unsigned u; float f; } v; v.u = u << 16; return v.f;
}

// ---------------- kernel 1: per-sample effective weights + bf16 MFMA B-fragments ----
// 24 blocks = 4 samples x 6 sections. Also computes S[n]=sum_c w1g (w1g = w1e*ln1w,
// bf16-rounded to match fragments) and Bn[n]=b1+sum_c w1e*ln1b for the LN-folded conv1.
__global__ __launch_bounds__(256) void k_weights(const float* __restrict__ probs,
    const float* __restrict__ w1, const float* __restrict__ la1, const float* __restrict__ lb1,
    const float* __restrict__ w2, const float* __restrict__ la2, const float* __restrict__ lb2,
    const float* __restrict__ wsca, const float* __restrict__ lasca, const float* __restrict__ lbsca,
    const float* __restrict__ w3, const float* __restrict__ la3, const float* __restrict__ lb3,
    const float* __restrict__ w4, const float* __restrict__ la4, const float* __restrict__ lb4,
    const float* __restrict__ w5, const float* __restrict__ la5, const float* __restrict__ lb5,
    const float* __restrict__ b3, const float* __restrict__ b5,
    const float* __restrict__ beta, const float* __restrict__ gamma,
    const float* __restrict__ ln1w, const float* __restrict__ ln1b, const float* __restrict__ b1,
    float* __restrict__ weff, U16* __restrict__ fragw)
{
  __shared__ float sb[5952];
  int blk = blockIdx.x;
  int b = blk / 6, sec = blk - b * 6;
  int tid = threadIdx.x;
  float p0 = probs[b*3+0], p1 = probs[b*3+1], p2 = probs[b*3+2];
  int e = 0; float g = p0;
  if (p1 > g) { g = p1; e = 1; }
  if (p2 > g) { g = p2; e = 2; }
  float s = 2.0f * g;               // SCALING * gate
  float* wfp = weff + b * WST;
  U16* fws = fragw + b * 24576;

  if (sec == 1) {
    // ---- w2e (depthwise 3x3, 1152) + folded biases + S/Bn for conv1 LN-fold ----
    const float* lbs = lb2 + e * 4608;
    const float* las = la2 + e * 36;
    for (int i = tid; i < 4608; i += 256) sb[i] = lbs[i];
    if (tid < 36) sb[4608 + tid] = las[tid];
    if (tid < 64) {
      sb[4644 + tid] = b3[tid];  sb[4708 + tid] = b5[tid];
      sb[4772 + tid] = beta[tid]; sb[4836 + tid] = gamma[tid];
      sb[5668 + tid] = ln1w[tid]; sb[5732 + tid] = ln1b[tid];
    }
    if (tid < 256) sb[4900 + tid] = la1[e*256 + tid];
    for (int i = tid; i < 512; i += 256) sb[5156 + i] = lb1[e*512 + i];
    if (tid < 128) sb[5796 + tid] = b1[tid];
    __syncthreads();
    for (int idx = tid; idx < 1152; idx += 256) {
      int row = idx / 3, dx = idx - row * 3;
      float acc = w2[idx];
      #pragma unroll
      for (int r = 0; r < 12; ++r)
        acc += s * sb[row*12 + r] * sb[4608 + r*3 + dx];
      wfp[8192 + idx] = acc;
    }
    if (tid < 64) {
      wfp[29824 + tid] = sb[4644 + tid] * sb[4772 + tid];   // b3 * beta
      wfp[29888 + tid] = sb[4708 + tid] * sb[4836 + tid];   // b5 * gamma
    }
    if (tid >= 128) {
      int n = tid - 128;
      float S = 0.f, Bn = sb[5796 + n];
      for (int c = 0; c < 64; ++c) {
        float wv = w1[n*64 + c];
        #pragma unroll
        for (int r = 0; r < 4; ++r) wv += s * sb[5156 + n*4 + r] * sb[4900 + r*64 + c];
        S  += bf2f(f2bf(wv * sb[5668 + c]));    // match fragment rounding
        Bn += wv * sb[5732 + c];
      }
      wfp[n] = S; wfp[128 + n] = Bn;
    }
    return;
  }
  if (sec == 2) {
    // ---- wscat [c][k] @9344 (4096) ----
    const float* lbs = lbsca + e * 256;
    const float* las = lasca + e * 256;
    if (tid < 256) { sb[tid] = lbs[tid]; sb[256 + tid] = las[tid]; }
    __syncthreads();
    #pragma unroll 4
    for (int idx = tid; idx < 4096; idx += 256) {
      int c = idx >> 6, k = idx & 63;
      float acc = wsca[k*64 + c];
      #pragma unroll
      for (int r = 0; r < 4; ++r)
        acc += s * sb[k*4 + r] * sb[256 + r*64 + c];
      wfp[9344 + idx] = acc;
    }
    return;
  }

  // ---- fragment sections: value = (w[n*64+k] + s*lb[n][:]@la[:][k]) * scale ----
  const float *w, *la, *lb, *scl = nullptr;
  bool sclk = false;
  int fo, cnt;
  if (sec == 0)      { w = w1; lb = lb1 + e*512; la = la1 + e*256; fo = 0;     cnt = 8192; scl = ln1w; sclk = true; }
  else if (sec == 3) { w = w3; lb = lb3 + e*256; la = la3 + e*256; fo = 8192;  cnt = 4096; scl = beta; }
  else if (sec == 4) { w = w4; lb = lb4 + e*512; la = la4 + e*256; fo = 12288; cnt = 8192; }
  else               { w = w5; lb = lb5 + e*256; la = la5 + e*256; fo = 20480; cnt = 4096; scl = gamma; }
  int nlb = (cnt == 8192) ? 512 : 256;
  for (int i = tid; i < nlb; i += 256) sb[i] = lb[i];
  if (tid < 256) sb[512 + tid] = la[tid];
  if (scl && tid < 64) sb[768 + tid] = scl[tid];
  __syncthreads();
  #pragma unroll 4
  for (int idx = tid; idx < cnt; idx += 256) {
    int j = idx & 7, l = (idx >> 3) & 63, s2 = (idx >> 9) & 1, nt = idx >> 10;
    int n = nt*16 + (l & 15), k = s2*32 + ((l >> 4) << 3) + j;
    float acc = w[n*64 + k];
    #pragma unroll
    for (int r = 0; r < 4; ++r)
      acc += s * sb[n*4 + r] * sb[512 + r*64 + k];
    if (scl) acc *= sb[768 + (sclk ? k : n)];
    fws[fo + idx] = f2bf(acc);
  }
}

// ---------------- kernel 2 (fused): LN1 + conv1 (MFMA) + dw3x3 + SimpleGate + pool ----
// block = (b, group, 8x32 tile). t1 never leaves LDS. Group g computes gated
// channels g*32..g*32+31 (t1 channels g*32+i and 64+g*32+i). 2048 blocks.
// blockIdx swizzle: the (g=0,g=1) twins of a tile read the SAME 340x64 inp
// window; placing them 8 blockIdx apart puts them back-to-back on one XCD
// (round-robin dispatch) so the twin's fetch is an L2 hit -> halves FETCH.
#define MTS 22   // m-tiles for 340 halo px
__global__ __launch_bounds__(256, 3) void k_stage1f(
    const float* __restrict__ inp, const float* __restrict__ b2,
    const float* __restrict__ weff, const U16* __restrict__ fragw,
    U16* __restrict__ z, float* __restrict__ pooled)
{
  __shared__ __align__(16) U16 smu[22528];   // union: afrag (22*1024) / t1s (64*348)
  __shared__ float2 muinv[344];
  __shared__ float poolbuf[4][16];
  int blk = blockIdx.x;
  // XCD-paired swizzle: xcd = blk&7, slot = blk>>3; g toggles fastest per XCD.
  int sslot = blk >> 3;
  int g = sslot & 1;
  int P = (blk & 7) + 8 * (sslot >> 1);    // pair id 0..1023 = (b, tile)
  int b = P >> 8;
  int tile = P & 255;
  int h0 = (tile >> 3) * 8, w0 = (tile & 7) * 32;
  int tid = threadIdx.x, lane = tid & 63, w = tid >> 6;
  const float* wfp = weff + b * WST;
  const U16* fw = fragw + b * 24576;

  // ---- P1: raw inp -> mu/inv + bf16 A-frags (no normalize; LN folded in epilogue) ----
  for (int it = 0; it < 2; ++it) {
    int i = tid + it * 256;
    if (i >= 340) break;
    int hy = i / 34, hx = i - hy * 34;
    int h = h0 - 1 + hy, ww = w0 - 1 + hx;
    int mt = i >> 4, m = i & 15;
    if (h >= 0 && h < 256 && ww >= 0 && ww < 256) {
      const float* src = inp + (size_t)b * 64 * HW + h * 256 + ww;
      float x[64];
      #pragma unroll
      for (int c = 0; c < 64; ++c) x[c] = src[(size_t)c * HW];
      float s0=0,s1=0,q0=0,q1=0;
      #pragma unroll
      for (int c = 0; c < 64; c += 2) {
        s0 += x[c];   q0 += x[c]*x[c];
        s1 += x[c+1]; q1 += x[c+1]*x[c+1];
      }
      float mu  = (s0+s1) * (1.f/64.f);
      float inv = rsqrtf(fmaxf((q0+q1)*(1.f/64.f) - mu*mu, 0.f) + 1e-6f);
      muinv[i] = float2{mu, inv};
      #pragma unroll
      for (int s = 0; s < 2; ++s)
        #pragma unroll
        for (int q = 0; q < 4; ++q) {
          union { unsigned u[4]; short8 v; } pk;
          #pragma unroll
          for (int j = 0; j < 4; ++j)
            pk.u[j] = pack2(x[s*32 + q*8 + 2*j], x[s*32 + q*8 + 2*j + 1]);
          *(short8*)&smu[mt*1024 + s*512 + (q*16 + m)*8] = pk.v;
        }
    } else {
      muinv[i] = float2{0.f, 0.f};   // inv==0 flags "outside image" -> t1 = 0
    }
  }

  // B-frags + S/Bn for this group's 4 n-tiles (done pre-barrier; independent of LDS)
  int n15 = lane & 15;
  short8 bw[8];
  float Sr[4], Br[4];
  #pragma unroll
  for (int ntl = 0; ntl < 4; ++ntl) {
    int ntg = (ntl < 2) ? (g*2 + ntl) : (4 + g*2 + (ntl - 2));
    #pragma unroll
    for (int s = 0; s < 2; ++s)
      bw[ntl*2 + s] = *(const short8*)&fw[((ntg*2 + s)*64 + lane)*8];
    int ng = ntg*16 + n15;
    Sr[ntl] = wfp[ng];
    Br[ntl] = wfp[128 + ng];
  }
  __syncthreads();

  // ---- P2: MFMA (raw-x conv1 with pre-scaled weights) ----
  int mt0 = w * 6;
  int nmt = MTS - mt0; if (nmt > 6) nmt = 6;   // 6,6,6,4
  float4v acc[6][4];
  #pragma unroll
  for (int mi = 0; mi < 6; ++mi)
    #pragma unroll
    for (int ntl = 0; ntl < 4; ++ntl) acc[mi][ntl] = (float4v)(0.f);
  #pragma unroll
  for (int mi = 0; mi < 6; ++mi) {
    if (mi < nmt) {
      int mt = mt0 + mi;
      #pragma unroll
      for (int s = 0; s < 2; ++s) {
        short8 a = *(const short8*)&smu[mt*1024 + s*512 + lane*8];
        #pragma unroll
        for (int ntl = 0; ntl < 4; ++ntl)
          acc[mi][ntl] = __builtin_amdgcn_mfma_f32_16x16x32_bf16(a, bw[ntl*2 + s], acc[mi][ntl], 0, 0, 0);
      }
    }
  }
  __syncthreads();   // afrag dead; smu becomes t1s[64][348]

  // ---- P3: epilogue t1 = inv*(A - mu*S) + Bn (0 outside image) -> t1s ----
  int q = lane >> 4;
  #pragma unroll
  for (int mi = 0; mi < 6; ++mi) {
    if (mi < nmt) {
      int px0 = (mt0 + mi)*16 + q*4;
      if (px0 < 340) {
        float2 m0 = muinv[px0], m1 = muinv[px0+1], m2 = muinv[px0+2], m3 = muinv[px0+3];
        #pragma unroll
        for (int ntl = 0; ntl < 4; ++ntl) {
          float S = Sr[ntl], B = Br[ntl];
          float v0 = m0.y*(acc[mi][ntl][0] - m0.x*S) + B;
          float v1 = m1.y*(acc[mi][ntl][1] - m1.x*S) + B;
          float v2 = m2.y*(acc[mi][ntl][2] - m2.x*S) + B;
          float v3 = m3.y*(acc[mi][ntl][3] - m3.x*S) + B;
          v0 = m0.y > 0.f ? v0 : 0.f;
          v1 = m1.y > 0.f ? v1 : 0.f;
          v2 = m2.y > 0.f ? v2 : 0.f;
          v3 = m3.y > 0.f ? v3 : 0.f;
          union { unsigned u[2]; us4 v; } pk;
          pk.u[0] = pack2(v0, v1);
          pk.u[1] = pack2(v2, v3);
          *(us4*)&smu[(ntl*16 + n15)*348 + px0] = pk.v;
        }
      }
    }
  }
  __syncthreads();

  // ---- P4: depthwise 3x3 + gate + z write + pool ----
  // thread = (channel half, 2-px pair). taps for even pair = 2 aligned dwords/row.
  {
    int half = tid >> 7;               // wave-uniform
    int pp = (tid & 127) * 2;
    int cy = pp >> 5, cx = pp & 31;
    const float* w2e = wfp + 8192;
    U16* zb = z + (size_t)b*64*HW + (size_t)(h0 + cy)*256 + (w0 + cx);
    #pragma unroll 2
    for (int i = 0; i < 16; ++i) {
      int kl = half*16 + i;
      int kg = g*32 + kl;
      unsigned ua[3][2], uc[3][2];
      #pragma unroll
      for (int dy = 0; dy < 3; ++dy) {
        int basea = kl*348 + (cy + dy)*34 + cx;
        int basec = (32 + kl)*348 + (cy + dy)*34 + cx;
        ua[dy][0] = *(unsigned*)&smu[basea]; ua[dy][1] = *(unsigned*)&smu[basea + 2];
        uc[dy][0] = *(unsigned*)&smu[basec]; uc[dy][1] = *(unsigned*)&smu[basec + 2];
      }
      const float* wa = w2e + kg*9;
      const float* wc = w2e + (kg + 64)*9;
      float a0 = b2[kg], a1 = a0;
      float c0 = b2[kg + 64], c1 = c0;
      #pragma unroll
      for (int dy = 0; dy < 3; ++dy) {
        float x0 = asflo(ua[dy][0]), x1 = asfhi(ua[dy][0]), x2 = asflo(ua[dy][1]), x3 = asfhi(ua[dy][1]);
        a0 += wa[dy*3]*x0 + wa[dy*3+1]*x1 + wa[dy*3+2]*x2;
        a1 += wa[dy*3]*x1 + wa[dy*3+1]*x2 + wa[dy*3+2]*x3;
        x0 = asflo(uc[dy][0]); x1 = asfhi(uc[dy][0]); x2 = asflo(uc[dy][1]); x3 = asfhi(uc[dy][1]);
        c0 += wc[dy*3]*x0 + wc[dy*3+1]*x1 + wc[dy*3+2]*x2;
        c1 += wc[dy*3]*x1 + wc[dy*3+1]*x2 + wc[dy*3+2]*x3;
      }
      float z0 = a0*c0, z1 = a1*c1;
      *(unsigned*)(zb + (size_t)kg * HW) = pack2(z0, z1);
      float ps = z0 + z1;
      #pragma unroll
      for (int off = 32; off >= 1; off >>= 1) ps += __shfl_down(ps, off, 64);
      if (lane == 0) poolbuf[w][i] = ps;
    }
  }
  __syncthreads();
  if (tid < 32) {
    float v = (tid < 16) ? (poolbuf[0][tid] + poolbuf[1][tid])
                         : (poolbuf[2][tid - 16] + poolbuf[3][tid - 16]);
    atomicAdd(&pooled[b*64 + g*32 + tid], v);
  }
}

// ---------------- kernel 3: sca[b][k] ----------------
__global__ void k_sca(const float* __restrict__ bsca, const float* __restrict__ weff,
                      const float* __restrict__ pooled, float* __restrict__ sca)
{
  int b = blockIdx.x, k = threadIdx.x;   // 64 threads
  const float* wt = weff + b * WST + 9344;   // wscat [c][k]
  const float* pm = pooled + b * 64;
  float acc = bsca[k];
  for (int c = 0; c < 64; ++c) acc += wt[c * 64 + k] * (pm[c] * (1.f/65536.f));
  sca[b * 64 + k] = acc;
}

// ---------------- kernel 4: xsca -> conv3 -> +inp (beta folded) -> LN2 -> conv4 -> gate -> conv5 ----
// block = (b, h): one image row. MFMA for conv3/conv4/conv5; per-pixel ops via LDS round-trips.
__global__ __launch_bounds__(256, 2) void k_stage2(
    const float* __restrict__ inp, const U16* __restrict__ z, const float* __restrict__ sca,
    const float* __restrict__ ln2w, const float* __restrict__ ln2b, const float* __restrict__ b4,
    const float* __restrict__ weff, const U16* __restrict__ fragw, float* __restrict__ out)
{
  __shared__ __align__(16) U16 yb[256*72];      // y, bf16, stride 72
  __shared__ __align__(16) char afr[34816];     // afrag U16[16384] / afragF float[256*33]
  U16* afrag = (U16*)afr;
  float* afragF = (float*)afr;
  int blk = blockIdx.x;
  int b = blk >> 8, h = blk & 255;
  int tid = threadIdx.x, lane = tid & 63, w = tid >> 6;
  const float* wb = weff + b * WST;
  const U16* fw = fragw + b * 24576;

  float y0[64];
  { // phase A: xs = z*sca -> A-frags; y0 = inp row
    const U16* zp = z + (size_t)b*64*HW + h*256 + tid;
    const float* scb = sca + b*64;
    float xs[64];
    #pragma unroll
    for (int k = 0; k < 64; ++k) xs[k] = bf2f(zp[(size_t)k * HW]) * scb[k];
    int mt = tid >> 4, m = tid & 15;
    #pragma unroll
    for (int s = 0; s < 2; ++s)
      #pragma unroll
      for (int q = 0; q < 4; ++q) {
        union { unsigned u[4]; short8 v; } pk;
        #pragma unroll
        for (int j = 0; j < 4; ++j)
          pk.u[j] = pack2(xs[s*32 + q*8 + 2*j], xs[s*32 + q*8 + 2*j + 1]);
        *(short8*)&afrag[mt*1024 + s*512 + (q*16 + m)*8] = pk.v;
      }
    const float* ip = inp + (size_t)b*64*HW + h*256 + tid;
    #pragma unroll
    for (int c = 0; c < 64; ++c) y0[c] = ip[(size_t)c * HW];
  }
  __syncthreads();

  { // conv3: [256x64] @ w3bt[64x64] -> yb (bf16, pre-residual)
    short8 bw3[8];
    #pragma unroll
    for (int i = 0; i < 8; ++i) bw3[i] = *(const short8*)&fw[8192 + (i*64 + lane)*8];
    float4v acc[4][4];
    #pragma unroll
    for (int mi = 0; mi < 4; ++mi)
      #pragma unroll
      for (int nt = 0; nt < 4; ++nt) acc[mi][nt] = (float4v)(0.f);
    #pragma unroll
    for (int mi = 0; mi < 4; ++mi) {
      int mt = w*4 + mi;
      #pragma unroll
      for (int s = 0; s < 2; ++s) {
        short8 a = *(const short8*)&afrag[mt*1024 + s*512 + lane*8];
        #pragma unroll
        for (int nt = 0; nt < 4; ++nt)
          acc[mi][nt] = __builtin_amdgcn_mfma_f32_16x16x32_bf16(a, bw3[nt*2 + s], acc[mi][nt], 0, 0, 0);
      }
    }
    #pragma unroll
    for (int mi = 0; mi < 4; ++mi) {
      int pxb = (w*4 + mi)*16 + ((lane >> 4) << 2);
      #pragma unroll
      for (int nt = 0; nt < 4; ++nt) {
        int c = nt*16 + (lane & 15);
        #pragma unroll
        for (int r = 0; r < 4; ++r)
          yb[(pxb + r)*72 + c] = f2bf(acc[mi][nt][r]);
      }
    }
  }
  __syncthreads();

  { // phase C (thread = pixel): residual + LN2 -> xln A-frags; write y back (bf16)
    const float* b3b = wb + 29824;
    float y[64];
    #pragma unroll
    for (int c8 = 0; c8 < 8; ++c8) {
      short8 v = *(const short8*)&yb[tid*72 + c8*8];
      #pragma unroll
      for (int j = 0; j < 8; ++j) y[c8*8 + j] = bf2f((U16)v[j]);
    }
    #pragma unroll
    for (int c = 0; c < 64; ++c) y[c] += y0[c] + b3b[c];
    float s0=0,s1=0,q0=0,q1=0;
    #pragma unroll
    for (int c = 0; c < 64; c += 2) {
      s0 += y[c];   q0 += y[c]*y[c];
      s1 += y[c+1]; q1 += y[c+1]*y[c+1];
    }
    float mu  = (s0+s1) * (1.f/64.f);
    float inv = rsqrtf((q0+q1) * (1.f/64.f) - mu*mu + 1e-6f);
    int mt = tid >> 4, m = tid & 15;
    #pragma unroll
    for (int s = 0; s < 2; ++s)
      #pragma unroll
      for (int q = 0; q < 4; ++q) {
        union { unsigned u[4]; short8 v; } pk;
        #pragma unroll
        for (int j = 0; j < 4; ++j) {
          int c = s*32 + q*8 + 2*j;
          float e0 = (y[c]   - mu) * inv * ln2w[c]   + ln2b[c];
          float e1 = (y[c+1] - mu) * inv * ln2w[c+1] + ln2b[c+1];
          pk.u[j] = pack2(e0, e1);
        }
        *(short8*)&afrag[mt*1024 + s*512 + (q*16 + m)*8] = pk.v;
      }
    #pragma unroll
    for (int c8 = 0; c8 < 8; ++c8) {
      union { unsigned u[4]; short8 v; } pk;
      #pragma unroll
      for (int j = 0; j < 4; ++j)
        pk.u[j] = pack2(y[c8*8 + 2*j], y[c8*8 + 2*j + 1]);
      *(short8*)&yb[tid*72 + c8*8] = pk.v;
    }
  }
  __syncthreads();

  float4v acc5[4][4];
  { // conv4 (64->128) + in-register SimpleGate -> g A-frags (own-wave region) -> conv5
    short8 bw4[16];
    #pragma unroll
    for (int i = 0; i < 16; ++i) bw4[i] = *(const short8*)&fw[12288 + (i*64 + lane)*8];
    float b4a[8];
    #pragma unroll
    for (int nt = 0; nt < 8; ++nt) b4a[nt] = b4[nt*16 + (lane & 15)];
    float4v acc[4][8];
    #pragma unroll
    for (int mi = 0; mi < 4; ++mi)
      #pragma unroll
      for (int nt = 0; nt < 8; ++nt) acc[mi][nt] = (float4v)(0.f);
    #pragma unroll
    for (int mi = 0; mi < 4; ++mi) {
      int mt = w*4 + mi;
      #pragma unroll
      for (int s = 0; s < 2; ++s) {
        short8 a = *(const short8*)&afrag[mt*1024 + s*512 + lane*8];
        #pragma unroll
        for (int nt = 0; nt < 8; ++nt)
          acc[mi][nt] = __builtin_amdgcn_mfma_f32_16x16x32_bf16(a, bw4[nt*2 + s], acc[mi][nt], 0, 0, 0);
      }
    }
    // gate: t4[px][k] * t4[px][k+64] — same lane, same reg across nt / nt+4
    #pragma unroll
    for (int mi = 0; mi < 4; ++mi) {
      int mt = w*4 + mi;
      int mloc = ((lane >> 4) << 2);
      #pragma unroll
      for (int nt = 0; nt < 4; ++nt) {
        int k = nt*16 + (lane & 15);
        int s_ = k >> 5, q = (k >> 3) & 3, j = k & 7;
        #pragma unroll
        for (int r = 0; r < 4; ++r) {
          float gv = (acc[mi][nt][r] + b4a[nt]) * (acc[mi][nt+4][r] + b4a[nt+4]);
          afrag[mt*1024 + s_*512 + (q*16 + mloc + r)*8 + j] = f2bf(gv);
        }
      }
    }
    // conv5 reads only own-wave region (RAW within wave: no barrier needed)
    short8 bw5[8];
    #pragma unroll
    for (int i = 0; i < 8; ++i) bw5[i] = *(const short8*)&fw[20480 + (i*64 + lane)*8];
    #pragma unroll
    for (int mi = 0; mi < 4; ++mi)
      #pragma unroll
      for (int nt = 0; nt < 4; ++nt) acc5[mi][nt] = (float4v)(0.f);
    #pragma unroll
    for (int mi = 0; mi < 4; ++mi) {
      int mt = w*4 + mi;
      #pragma unroll
      for (int s = 0; s < 2; ++s) {
        short8 a = *(const short8*)&afrag[mt*1024 + s*512 + lane*8];
        #pragma unroll
        for (int nt = 0; nt < 4; ++nt)
          acc5[mi][nt] = __builtin_amdgcn_mfma_f32_16x16x32_bf16(a, bw5[nt*2 + s], acc5[mi][nt], 0, 0, 0);
      }
    }
  }
  __syncthreads();   // all afrag reads done before fp32 reuse (regions overlap across waves)

  { // epilogue: out = y + b5g + conv5, fp32, coalesced via LDS transpose (own-wave rows)
    const float* b5g = wb + 29888;
    float b5f[4];
    #pragma unroll
    for (int nt = 0; nt < 4; ++nt) b5f[nt] = b5g[nt*16 + (lane & 15)];
    float* op = out + (size_t)b*64*HW + h*256;
    for (int chalf = 0; chalf < 2; ++chalf) {
      #pragma unroll
      for (int mi = 0; mi < 4; ++mi) {
        int pxb = (w*4 + mi)*16 + ((lane >> 4) << 2);
        #pragma unroll
        for (int nt2 = 0; nt2 < 2; ++nt2) {
          int nt = chalf*2 + nt2;
          int c = nt*16 + (lane & 15);
          #pragma unroll
          for (int r = 0; r < 4; ++r) {
            float v = acc5[mi][nt][r] + b5f[nt] + bf2f(yb[(pxb + r)*72 + c]);
            afragF[(pxb + r)*33 + (c - chalf*32)] = v;
          }
        }
      }
      // own-wave rows: thread tid reads row tid (written by its own wave) — no barrier needed
      #pragma unroll 4
      for (int cc = 0; cc < 32; ++cc)
        op[(size_t)(chalf*32 + cc) * HW + tid] = afragF[tid*33 + cc];
    }
  }
}

extern "C" void kernel_launch(void* const* d_in, const int* in_sizes, int n_in,
                              void* d_out, int out_size, void* d_ws, size_t ws_size,
                              hipStream_t stream) {
  const float* inp   = (const float*)d_in[0];
  const float* probs = (const float*)d_in[1];
  const float* ln1w  = (const float*)d_in[2];
  const float* ln1b  = (const float*)d_in[3];
  const float* ln2w  = (const float*)d_in[4];
  const float* ln2b  = (const float*)d_in[5];
  const float* w1    = (const float*)d_in[6];
  const float* b1    = (const float*)d_in[7];
  const float* la1   = (const float*)d_in[8];
  const float* lb1   = (const float*)d_in[9];
  const float* w2    = (const float*)d_in[10];
  const float* b2    = (const float*)d_in[11];
  const float* la2   = (const float*)d_in[12];
  const float* lb2   = (const float*)d_in[13];
  const float* wsca  = (const float*)d_in[14];
  const float* bsca  = (const float*)d_in[15];
  const float* lasca = (const float*)d_in[16];
  const float* lbsca = (const float*)d_in[17];
  const float* w3    = (const float*)d_in[18];
  const float* b3    = (const float*)d_in[19];
  const float* la3   = (const float*)d_in[20];
  const float* lb3   = (const float*)d_in[21];
  const float* w4    = (const float*)d_in[22];
  const float* b4    = (const float*)d_in[23];
  const float* la4   = (const float*)d_in[24];
  const float* lb4   = (const float*)d_in[25];
  const float* w5    = (const float*)d_in[26];
  const float* b5    = (const float*)d_in[27];
  const float* la5   = (const float*)d_in[28];
  const float* lb5   = (const float*)d_in[29];
  const float* beta  = (const float*)d_in[30];
  const float* gamma = (const float*)d_in[31];

  char* wsb = (char*)d_ws;
  float* weff   = (float*)(wsb + WEFF_OFF);
  U16*   fragw  = (U16*)(wsb + FRAG_OFF);
  float* pooled = (float*)(wsb + POOL_OFF);
  float* scap   = (float*)(wsb + SCA_OFF);
  U16*   zws    = (U16*)(wsb + Z_OFF);
  float* outp   = (float*)d_out;

  hipMemsetAsync(pooled, 0, 256 * sizeof(float), stream);
  k_weights<<<dim3(24), dim3(256), 0, stream>>>(probs,
      w1, la1, lb1, w2, la2, lb2, wsca, lasca, lbsca,
      w3, la3, lb3, w4, la4, lb4, w5, la5, lb5,
      b3, b5, beta, gamma, ln1w, ln1b, b1, weff, fragw);
  k_stage1f<<<dim3(2048), dim3(256), 0, stream>>>(inp, b2, weff, fragw, zws, pooled);
  k_sca<<<dim3(4), dim3(64), 0, stream>>>(bsca, weff, pooled, scap);
  k_stage2<<<dim3(1024), dim3(256), 0, stream>>>(inp, zws, scap, ln2w, ln2b, b4, weff, fragw, outp);
}

// Round 7
// 280.962 us; speedup vs baseline: 1.0802x; 1.0401x over previous
//
#include <hip/hip_runtime.h>
#include <hip/hip_bf16.h>

#define HW 65536
#define WST 29952   // per-sample fp32 effective-weight stride (floats)

typedef unsigned short U16;
typedef __attribute__((ext_vector_type(8))) short short8;
typedef __attribute__((ext_vector_type(4))) unsigned short us4;
typedef __attribute__((ext_vector_type(4))) float float4v;

// ws byte offsets
#define WEFF_OFF 0
#define FRAG_OFF 524288        // U16[4][24576]: w1f@0, w3f@8192, w4f@12288, w5f@20480
#define POOL_OFF 786432        // float[256]
#define Z_OFF    68157440      // U16[4][64][HW]

__device__ inline U16 f2bf(float f) {
  union { float f; unsigned u; } v; v.f = f;
  unsigned r = v.u + 0x7FFF + ((v.u >> 16) & 1);   // RNE
  return (U16)(r >> 16);
}
// packed RNE pair conversion via HIP intrinsic (compiler lowers to packed cvt;
// numerically identical RNE to f2bf). low 16 bits = a, high = b.
__device__ inline unsigned pack2(float a, float b) {
  union { __hip_bfloat162 h; unsigned u; } v;
  v.h = __float22bfloat162_rn(float2{a, b});
  return v.u;
}
__device__ inline float bf2f(U16 h) {
  union { unsigned u; float f; } v; v.u = ((unsigned)h) << 16;
  return v.f;
}
__device__ inline float asfhi(unsigned u) {   // high bf16 of dword
  union { unsigned u; float f; } v; v.u = u & 0xffff0000u; return v.f;
}
__device__ inline float asflo(unsigned u) {   // low bf16 of dword
  union { unsigned u; float f; } v; v.u = u << 16; return v.f;
}

// ---------------- kernel 1: per-sample effective weights + bf16 MFMA B-fragments ----
// 24 blocks = 4 samples x 6 sections. Also computes S[n]=sum_c w1g (w1g = w1e*ln1w,
// bf16-rounded to match fragments) and Bn[n]=b1+sum_c w1e*ln1b for the LN-folded conv1.
// Block blk==2 additionally zeroes pooled[256] (replaces the hipMemsetAsync dispatch;
// stream order puts k_weights before k_stage1f's atomics).
__global__ __launch_bounds__(256) void k_weights(const float* __restrict__ probs,
    const float* __restrict__ w1, const float* __restrict__ la1, const float* __restrict__ lb1,
    const float* __restrict__ w2, const float* __restrict__ la2, const float* __restrict__ lb2,
    const float* __restrict__ wsca, const float* __restrict__ lasca, const float* __restrict__ lbsca,
    const float* __restrict__ w3, const float* __restrict__ la3, const float* __restrict__ lb3,
    const float* __restrict__ w4, const float* __restrict__ la4, const float* __restrict__ lb4,
    const float* __restrict__ w5, const float* __restrict__ la5, const float* __restrict__ lb5,
    const float* __restrict__ b3, const float* __restrict__ b5,
    const float* __restrict__ beta, const float* __restrict__ gamma,
    const float* __restrict__ ln1w, const float* __restrict__ ln1b, const float* __restrict__ b1,
    float* __restrict__ weff, U16* __restrict__ fragw, float* __restrict__ pooled)
{
  __shared__ float sb[5952];
  int blk = blockIdx.x;
  int b = blk / 6, sec = blk - b * 6;
  int tid = threadIdx.x;
  if (blk == 2) pooled[tid] = 0.f;     // zero the pool accumulator (256 floats)
  float p0 = probs[b*3+0], p1 = probs[b*3+1], p2 = probs[b*3+2];
  int e = 0; float g = p0;
  if (p1 > g) { g = p1; e = 1; }
  if (p2 > g) { g = p2; e = 2; }
  float s = 2.0f * g;               // SCALING * gate
  float* wfp = weff + b * WST;
  U16* fws = fragw + b * 24576;

  if (sec == 1) {
    // ---- w2e (depthwise 3x3, 1152) + folded biases + S/Bn for conv1 LN-fold ----
    const float* lbs = lb2 + e * 4608;
    const float* las = la2 + e * 36;
    for (int i = tid; i < 4608; i += 256) sb[i] = lbs[i];
    if (tid < 36) sb[4608 + tid] = las[tid];
    if (tid < 64) {
      sb[4644 + tid] = b3[tid];  sb[4708 + tid] = b5[tid];
      sb[4772 + tid] = beta[tid]; sb[4836 + tid] = gamma[tid];
      sb[5668 + tid] = ln1w[tid]; sb[5732 + tid] = ln1b[tid];
    }
    if (tid < 256) sb[4900 + tid] = la1[e*256 + tid];
    for (int i = tid; i < 512; i += 256) sb[5156 + i] = lb1[e*512 + i];
    if (tid < 128) sb[5796 + tid] = b1[tid];
    __syncthreads();
    for (int idx = tid; idx < 1152; idx += 256) {
      int row = idx / 3, dx = idx - row * 3;
      float acc = w2[idx];
      #pragma unroll
      for (int r = 0; r < 12; ++r)
        acc += s * sb[row*12 + r] * sb[4608 + r*3 + dx];
      wfp[8192 + idx] = acc;
    }
    if (tid < 64) {
      wfp[29824 + tid] = sb[4644 + tid] * sb[4772 + tid];   // b3 * beta
      wfp[29888 + tid] = sb[4708 + tid] * sb[4836 + tid];   // b5 * gamma
    }
    if (tid >= 128) {
      int n = tid - 128;
      float S = 0.f, Bn = sb[5796 + n];
      for (int c = 0; c < 64; ++c) {
        float wv = w1[n*64 + c];
        #pragma unroll
        for (int r = 0; r < 4; ++r) wv += s * sb[5156 + n*4 + r] * sb[4900 + r*64 + c];
        S  += bf2f(f2bf(wv * sb[5668 + c]));    // match fragment rounding
        Bn += wv * sb[5732 + c];
      }
      wfp[n] = S; wfp[128 + n] = Bn;
    }
    return;
  }
  if (sec == 2) {
    // ---- wscat [c][k] @9344 (4096) ----
    const float* lbs = lbsca + e * 256;
    const float* las = lasca + e * 256;
    if (tid < 256) { sb[tid] = lbs[tid]; sb[256 + tid] = las[tid]; }
    __syncthreads();
    #pragma unroll 4
    for (int idx = tid; idx < 4096; idx += 256) {
      int c = idx >> 6, k = idx & 63;
      float acc = wsca[k*64 + c];
      #pragma unroll
      for (int r = 0; r < 4; ++r)
        acc += s * sb[k*4 + r] * sb[256 + r*64 + c];
      wfp[9344 + idx] = acc;
    }
    return;
  }

  // ---- fragment sections: value = (w[n*64+k] + s*lb[n][:]@la[:][k]) * scale ----
  const float *w, *la, *lb, *scl = nullptr;
  bool sclk = false;
  int fo, cnt;
  if (sec == 0)      { w = w1; lb = lb1 + e*512; la = la1 + e*256; fo = 0;     cnt = 8192; scl = ln1w; sclk = true; }
  else if (sec == 3) { w = w3; lb = lb3 + e*256; la = la3 + e*256; fo = 8192;  cnt = 4096; scl = beta; }
  else if (sec == 4) { w = w4; lb = lb4 + e*512; la = la4 + e*256; fo = 12288; cnt = 8192; }
  else               { w = w5; lb = lb5 + e*256; la = la5 + e*256; fo = 20480; cnt = 4096; scl = gamma; }
  int nlb = (cnt == 8192) ? 512 : 256;
  for (int i = tid; i < nlb; i += 256) sb[i] = lb[i];
  if (tid < 256) sb[512 + tid] = la[tid];
  if (scl && tid < 64) sb[768 + tid] = scl[tid];
  __syncthreads();
  #pragma unroll 4
  for (int idx = tid; idx < cnt; idx += 256) {
    int j = idx & 7, l = (idx >> 3) & 63, s2 = (idx >> 9) & 1, nt = idx >> 10;
    int n = nt*16 + (l & 15), k = s2*32 + ((l >> 4) << 3) + j;
    float acc = w[n*64 + k];
    #pragma unroll
    for (int r = 0; r < 4; ++r)
      acc += s * sb[n*4 + r] * sb[512 + r*64 + k];
    if (scl) acc *= sb[768 + (sclk ? k : n)];
    fws[fo + idx] = f2bf(acc);
  }
}

// ---------------- kernel 2 (fused): LN1 + conv1 (MFMA) + dw3x3 + SimpleGate + pool ----
// block = (b, group, 8x32 tile). t1 never leaves LDS. Group g computes gated
// channels g*32..g*32+31 (t1 channels g*32+i and 64+g*32+i). 2048 blocks.
// blockIdx swizzle: the (g=0,g=1) twins of a tile read the SAME 340x64 inp
// window; placing them 8 blockIdx apart puts them back-to-back on one XCD
// (round-robin dispatch) so the twin's fetch is an L2 hit -> halves FETCH.
#define MTS 22   // m-tiles for 340 halo px
__global__ __launch_bounds__(256, 3) void k_stage1f(
    const float* __restrict__ inp, const float* __restrict__ b2,
    const float* __restrict__ weff, const U16* __restrict__ fragw,
    U16* __restrict__ z, float* __restrict__ pooled)
{
  __shared__ __align__(16) U16 smu[22528];   // union: afrag (22*1024) / t1s (64*348)
  __shared__ float2 muinv[344];
  __shared__ float poolbuf[4][16];
  int blk = blockIdx.x;
  // XCD-paired swizzle: xcd = blk&7, slot = blk>>3; g toggles fastest per XCD.
  int sslot = blk >> 3;
  int g = sslot & 1;
  int P = (blk & 7) + 8 * (sslot >> 1);    // pair id 0..1023 = (b, tile)
  int b = P >> 8;
  int tile = P & 255;
  int h0 = (tile >> 3) * 8, w0 = (tile & 7) * 32;
  int tid = threadIdx.x, lane = tid & 63, w = tid >> 6;
  const float* wfp = weff + b * WST;
  const U16* fw = fragw + b * 24576;

  // ---- P1: raw inp -> mu/inv + bf16 A-frags (no normalize; LN folded in epilogue) ----
  for (int it = 0; it < 2; ++it) {
    int i = tid + it * 256;
    if (i >= 340) break;
    int hy = i / 34, hx = i - hy * 34;
    int h = h0 - 1 + hy, ww = w0 - 1 + hx;
    int mt = i >> 4, m = i & 15;
    if (h >= 0 && h < 256 && ww >= 0 && ww < 256) {
      const float* src = inp + (size_t)b * 64 * HW + h * 256 + ww;
      float x[64];
      #pragma unroll
      for (int c = 0; c < 64; ++c) x[c] = src[(size_t)c * HW];
      float s0=0,s1=0,q0=0,q1=0;
      #pragma unroll
      for (int c = 0; c < 64; c += 2) {
        s0 += x[c];   q0 += x[c]*x[c];
        s1 += x[c+1]; q1 += x[c+1]*x[c+1];
      }
      float mu  = (s0+s1) * (1.f/64.f);
      float inv = rsqrtf(fmaxf((q0+q1)*(1.f/64.f) - mu*mu, 0.f) + 1e-6f);
      muinv[i] = float2{mu, inv};
      #pragma unroll
      for (int s = 0; s < 2; ++s)
        #pragma unroll
        for (int q = 0; q < 4; ++q) {
          union { unsigned u[4]; short8 v; } pk;
          #pragma unroll
          for (int j = 0; j < 4; ++j)
            pk.u[j] = pack2(x[s*32 + q*8 + 2*j], x[s*32 + q*8 + 2*j + 1]);
          *(short8*)&smu[mt*1024 + s*512 + (q*16 + m)*8] = pk.v;
        }
    } else {
      muinv[i] = float2{0.f, 0.f};   // inv==0 flags "outside image" -> t1 = 0
    }
  }

  // B-frags + S/Bn for this group's 4 n-tiles (done pre-barrier; independent of LDS)
  int n15 = lane & 15;
  short8 bw[8];
  float Sr[4], Br[4];
  #pragma unroll
  for (int ntl = 0; ntl < 4; ++ntl) {
    int ntg = (ntl < 2) ? (g*2 + ntl) : (4 + g*2 + (ntl - 2));
    #pragma unroll
    for (int s = 0; s < 2; ++s)
      bw[ntl*2 + s] = *(const short8*)&fw[((ntg*2 + s)*64 + lane)*8];
    int ng = ntg*16 + n15;
    Sr[ntl] = wfp[ng];
    Br[ntl] = wfp[128 + ng];
  }
  __syncthreads();

  // ---- P2: MFMA (raw-x conv1 with pre-scaled weights) ----
  int mt0 = w * 6;
  int nmt = MTS - mt0; if (nmt > 6) nmt = 6;   // 6,6,6,4
  float4v acc[6][4];
  #pragma unroll
  for (int mi = 0; mi < 6; ++mi)
    #pragma unroll
    for (int ntl = 0; ntl < 4; ++ntl) acc[mi][ntl] = (float4v)(0.f);
  #pragma unroll
  for (int mi = 0; mi < 6; ++mi) {
    if (mi < nmt) {
      int mt = mt0 + mi;
      #pragma unroll
      for (int s = 0; s < 2; ++s) {
        short8 a = *(const short8*)&smu[mt*1024 + s*512 + lane*8];
        #pragma unroll
        for (int ntl = 0; ntl < 4; ++ntl)
          acc[mi][ntl] = __builtin_amdgcn_mfma_f32_16x16x32_bf16(a, bw[ntl*2 + s], acc[mi][ntl], 0, 0, 0);
      }
    }
  }
  __syncthreads();   // afrag dead; smu becomes t1s[64][348]

  // ---- P3: epilogue t1 = inv*(A - mu*S) + Bn (0 outside image) -> t1s ----
  int q = lane >> 4;
  #pragma unroll
  for (int mi = 0; mi < 6; ++mi) {
    if (mi < nmt) {
      int px0 = (mt0 + mi)*16 + q*4;
      if (px0 < 340) {
        float2 m0 = muinv[px0], m1 = muinv[px0+1], m2 = muinv[px0+2], m3 = muinv[px0+3];
        #pragma unroll
        for (int ntl = 0; ntl < 4; ++ntl) {
          float S = Sr[ntl], B = Br[ntl];
          float v0 = m0.y*(acc[mi][ntl][0] - m0.x*S) + B;
          float v1 = m1.y*(acc[mi][ntl][1] - m1.x*S) + B;
          float v2 = m2.y*(acc[mi][ntl][2] - m2.x*S) + B;
          float v3 = m3.y*(acc[mi][ntl][3] - m3.x*S) + B;
          v0 = m0.y > 0.f ? v0 : 0.f;
          v1 = m1.y > 0.f ? v1 : 0.f;
          v2 = m2.y > 0.f ? v2 : 0.f;
          v3 = m3.y > 0.f ? v3 : 0.f;
          union { unsigned u[2]; us4 v; } pk;
          pk.u[0] = pack2(v0, v1);
          pk.u[1] = pack2(v2, v3);
          *(us4*)&smu[(ntl*16 + n15)*348 + px0] = pk.v;
        }
      }
    }
  }
  __syncthreads();

  // ---- P4: depthwise 3x3 + gate + z write + pool ----
  // thread = (channel half, 2-px pair). taps for even pair = 2 aligned dwords/row.
  {
    int half = tid >> 7;               // wave-uniform
    int pp = (tid & 127) * 2;
    int cy = pp >> 5, cx = pp & 31;
    const float* w2e = wfp + 8192;
    U16* zb = z + (size_t)b*64*HW + (size_t)(h0 + cy)*256 + (w0 + cx);
    #pragma unroll 2
    for (int i = 0; i < 16; ++i) {
      int kl = half*16 + i;
      int kg = g*32 + kl;
      unsigned ua[3][2], uc[3][2];
      #pragma unroll
      for (int dy = 0; dy < 3; ++dy) {
        int basea = kl*348 + (cy + dy)*34 + cx;
        int basec = (32 + kl)*348 + (cy + dy)*34 + cx;
        ua[dy][0] = *(unsigned*)&smu[basea]; ua[dy][1] = *(unsigned*)&smu[basea + 2];
        uc[dy][0] = *(unsigned*)&smu[basec]; uc[dy][1] = *(unsigned*)&smu[basec + 2];
      }
      const float* wa = w2e + kg*9;
      const float* wc = w2e + (kg + 64)*9;
      float a0 = b2[kg], a1 = a0;
      float c0 = b2[kg + 64], c1 = c0;
      #pragma unroll
      for (int dy = 0; dy < 3; ++dy) {
        float x0 = asflo(ua[dy][0]), x1 = asfhi(ua[dy][0]), x2 = asflo(ua[dy][1]), x3 = asfhi(ua[dy][1]);
        a0 += wa[dy*3]*x0 + wa[dy*3+1]*x1 + wa[dy*3+2]*x2;
        a1 += wa[dy*3]*x1 + wa[dy*3+1]*x2 + wa[dy*3+2]*x3;
        x0 = asflo(uc[dy][0]); x1 = asfhi(uc[dy][0]); x2 = asflo(uc[dy][1]); x3 = asfhi(uc[dy][1]);
        c0 += wc[dy*3]*x0 + wc[dy*3+1]*x1 + wc[dy*3+2]*x2;
        c1 += wc[dy*3]*x1 + wc[dy*3+1]*x2 + wc[dy*3+2]*x3;
      }
      float z0 = a0*c0, z1 = a1*c1;
      *(unsigned*)(zb + (size_t)kg * HW) = pack2(z0, z1);
      float ps = z0 + z1;
      #pragma unroll
      for (int off = 32; off >= 1; off >>= 1) ps += __shfl_down(ps, off, 64);
      if (lane == 0) poolbuf[w][i] = ps;
    }
  }
  __syncthreads();
  if (tid < 32) {
    float v = (tid < 16) ? (poolbuf[0][tid] + poolbuf[1][tid])
                         : (poolbuf[2][tid - 16] + poolbuf[3][tid - 16]);
    atomicAdd(&pooled[b*64 + g*32 + tid], v);
  }
}

// ---------------- kernel 3 (k_sca folded in): sca + xsca -> conv3 -> +inp (beta folded)
// -> LN2 -> conv4 -> gate -> conv5.  block = (b, h): one image row.
__global__ __launch_bounds__(256, 2) void k_stage2(
    const float* __restrict__ inp, const U16* __restrict__ z,
    const float* __restrict__ bsca, const float* __restrict__ pooled,
    const float* __restrict__ ln2w, const float* __restrict__ ln2b, const float* __restrict__ b4,
    const float* __restrict__ weff, const U16* __restrict__ fragw, float* __restrict__ out)
{
  __shared__ __align__(16) U16 yb[256*72];      // y, bf16, stride 72
  __shared__ __align__(16) char afr[34816];     // afrag U16[16384] / afragF float[256*33]
  __shared__ float spart[256];
  __shared__ float ssca[64];
  U16* afrag = (U16*)afr;
  float* afragF = (float*)afr;
  int blk = blockIdx.x;
  int b = blk >> 8, h = blk & 255;
  int tid = threadIdx.x, lane = tid & 63, w = tid >> 6;
  const float* wb = weff + b * WST;
  const U16* fw = fragw + b * 24576;

  { // phase 0: sca[b][k] = bsca[k] + sum_c wscat[c][k] * mean(pool) (was k_sca)
    int k = tid & 63, qq = tid >> 6;
    const float* wt = wb + 9344;               // wscat [c][k]
    const float* pm = pooled + b * 64;
    float part = 0.f;
    #pragma unroll
    for (int j = 0; j < 16; ++j) {
      int c = qq * 16 + j;
      part += wt[c * 64 + k] * (pm[c] * (1.f/65536.f));
    }
    spart[tid] = part;
  }
  __syncthreads();
  if (tid < 64)
    ssca[tid] = bsca[tid] + spart[tid] + spart[64 + tid] + spart[128 + tid] + spart[192 + tid];
  __syncthreads();

  float y0[64];
  { // phase A: xs = z*sca -> A-frags; y0 = inp row
    const U16* zp = z + (size_t)b*64*HW + h*256 + tid;
    float xs[64];
    #pragma unroll
    for (int k = 0; k < 64; ++k) xs[k] = bf2f(zp[(size_t)k * HW]) * ssca[k];
    int mt = tid >> 4, m = tid & 15;
    #pragma unroll
    for (int s = 0; s < 2; ++s)
      #pragma unroll
      for (int q = 0; q < 4; ++q) {
        union { unsigned u[4]; short8 v; } pk;
        #pragma unroll
        for (int j = 0; j < 4; ++j)
          pk.u[j] = pack2(xs[s*32 + q*8 + 2*j], xs[s*32 + q*8 + 2*j + 1]);
        *(short8*)&afrag[mt*1024 + s*512 + (q*16 + m)*8] = pk.v;
      }
    const float* ip = inp + (size_t)b*64*HW + h*256 + tid;
    #pragma unroll
    for (int c = 0; c < 64; ++c) y0[c] = ip[(size_t)c * HW];
  }
  __syncthreads();

  { // conv3: [256x64] @ w3bt[64x64] -> yb (bf16, pre-residual)
    short8 bw3[8];
    #pragma unroll
    for (int i = 0; i < 8; ++i) bw3[i] = *(const short8*)&fw[8192 + (i*64 + lane)*8];
    float4v acc[4][4];
    #pragma unroll
    for (int mi = 0; mi < 4; ++mi)
      #pragma unroll
      for (int nt = 0; nt < 4; ++nt) acc[mi][nt] = (float4v)(0.f);
    #pragma unroll
    for (int mi = 0; mi < 4; ++mi) {
      int mt = w*4 + mi;
      #pragma unroll
      for (int s = 0; s < 2; ++s) {
        short8 a = *(const short8*)&afrag[mt*1024 + s*512 + lane*8];
        #pragma unroll
        for (int nt = 0; nt < 4; ++nt)
          acc[mi][nt] = __builtin_amdgcn_mfma_f32_16x16x32_bf16(a, bw3[nt*2 + s], acc[mi][nt], 0, 0, 0);
      }
    }
    #pragma unroll
    for (int mi = 0; mi < 4; ++mi) {
      int pxb = (w*4 + mi)*16 + ((lane >> 4) << 2);
      #pragma unroll
      for (int nt = 0; nt < 4; ++nt) {
        int c = nt*16 + (lane & 15);
        #pragma unroll
        for (int r = 0; r < 4; ++r)
          yb[(pxb + r)*72 + c] = f2bf(acc[mi][nt][r]);
      }
    }
  }
  __syncthreads();

  { // phase C (thread = pixel): residual + LN2 -> xln A-frags; write y back (bf16)
    const float* b3b = wb + 29824;
    float y[64];
    #pragma unroll
    for (int c8 = 0; c8 < 8; ++c8) {
      short8 v = *(const short8*)&yb[tid*72 + c8*8];
      #pragma unroll
      for (int j = 0; j < 8; ++j) y[c8*8 + j] = bf2f((U16)v[j]);
    }
    #pragma unroll
    for (int c = 0; c < 64; ++c) y[c] += y0[c] + b3b[c];
    float s0=0,s1=0,q0=0,q1=0;
    #pragma unroll
    for (int c = 0; c < 64; c += 2) {
      s0 += y[c];   q0 += y[c]*y[c];
      s1 += y[c+1]; q1 += y[c+1]*y[c+1];
    }
    float mu  = (s0+s1) * (1.f/64.f);
    float inv = rsqrtf((q0+q1) * (1.f/64.f) - mu*mu + 1e-6f);
    int mt = tid >> 4, m = tid & 15;
    #pragma unroll
    for (int s = 0; s < 2; ++s)
      #pragma unroll
      for (int q = 0; q < 4; ++q) {
        union { unsigned u[4]; short8 v; } pk;
        #pragma unroll
        for (int j = 0; j < 4; ++j) {
          int c = s*32 + q*8 + 2*j;
          float e0 = (y[c]   - mu) * inv * ln2w[c]   + ln2b[c];
          float e1 = (y[c+1] - mu) * inv * ln2w[c+1] + ln2b[c+1];
          pk.u[j] = pack2(e0, e1);
        }
        *(short8*)&afrag[mt*1024 + s*512 + (q*16 + m)*8] = pk.v;
      }
    #pragma unroll
    for (int c8 = 0; c8 < 8; ++c8) {
      union { unsigned u[4]; short8 v; } pk;
      #pragma unroll
      for (int j = 0; j < 4; ++j)
        pk.u[j] = pack2(y[c8*8 + 2*j], y[c8*8 + 2*j + 1]);
      *(short8*)&yb[tid*72 + c8*8] = pk.v;
    }
  }
  __syncthreads();

  float4v acc5[4][4];
  { // conv4 (64->128) + in-register SimpleGate -> g A-frags (own-wave region) -> conv5
    short8 bw4[16];
    #pragma unroll
    for (int i = 0; i < 16; ++i) bw4[i] = *(const short8*)&fw[12288 + (i*64 + lane)*8];
    float b4a[8];
    #pragma unroll
    for (int nt = 0; nt < 8; ++nt) b4a[nt] = b4[nt*16 + (lane & 15)];
    float4v acc[4][8];
    #pragma unroll
    for (int mi = 0; mi < 4; ++mi)
      #pragma unroll
      for (int nt = 0; nt < 8; ++nt) acc[mi][nt] = (float4v)(0.f);
    #pragma unroll
    for (int mi = 0; mi < 4; ++mi) {
      int mt = w*4 + mi;
      #pragma unroll
      for (int s = 0; s < 2; ++s) {
        short8 a = *(const short8*)&afrag[mt*1024 + s*512 + lane*8];
        #pragma unroll
        for (int nt = 0; nt < 8; ++nt)
          acc[mi][nt] = __builtin_amdgcn_mfma_f32_16x16x32_bf16(a, bw4[nt*2 + s], acc[mi][nt], 0, 0, 0);
      }
    }
    // gate: t4[px][k] * t4[px][k+64] — same lane, same reg across nt / nt+4
    #pragma unroll
    for (int mi = 0; mi < 4; ++mi) {
      int mt = w*4 + mi;
      int mloc = ((lane >> 4) << 2);
      #pragma unroll
      for (int nt = 0; nt < 4; ++nt) {
        int k = nt*16 + (lane & 15);
        int s_ = k >> 5, q = (k >> 3) & 3, j = k & 7;
        #pragma unroll
        for (int r = 0; r < 4; ++r) {
          float gv = (acc[mi][nt][r] + b4a[nt]) * (acc[mi][nt+4][r] + b4a[nt+4]);
          afrag[mt*1024 + s_*512 + (q*16 + mloc + r)*8 + j] = f2bf(gv);
        }
      }
    }
    // conv5 reads only own-wave region (RAW within wave: no barrier needed)
    short8 bw5[8];
    #pragma unroll
    for (int i = 0; i < 8; ++i) bw5[i] = *(const short8*)&fw[20480 + (i*64 + lane)*8];
    #pragma unroll
    for (int mi = 0; mi < 4; ++mi)
      #pragma unroll
      for (int nt = 0; nt < 4; ++nt) acc5[mi][nt] = (float4v)(0.f);
    #pragma unroll
    for (int mi = 0; mi < 4; ++mi) {
      int mt = w*4 + mi;
      #pragma unroll
      for (int s = 0; s < 2; ++s) {
        short8 a = *(const short8*)&afrag[mt*1024 + s*512 + lane*8];
        #pragma unroll
        for (int nt = 0; nt < 4; ++nt)
          acc5[mi][nt] = __builtin_amdgcn_mfma_f32_16x16x32_bf16(a, bw5[nt*2 + s], acc5[mi][nt], 0, 0, 0);
      }
    }
  }
  __syncthreads();   // all afrag reads done before fp32 reuse (regions overlap across waves)

  { // epilogue: out = y + b5g + conv5, fp32, coalesced via LDS transpose (own-wave rows)
    const float* b5g = wb + 29888;
    float b5f[4];
    #pragma unroll
    for (int nt = 0; nt < 4; ++nt) b5f[nt] = b5g[nt*16 + (lane & 15)];
    float* op = out + (size_t)b*64*HW + h*256;
    for (int chalf = 0; chalf < 2; ++chalf) {
      #pragma unroll
      for (int mi = 0; mi < 4; ++mi) {
        int pxb = (w*4 + mi)*16 + ((lane >> 4) << 2);
        #pragma unroll
        for (int nt2 = 0; nt2 < 2; ++nt2) {
          int nt = chalf*2 + nt2;
          int c = nt*16 + (lane & 15);
          #pragma unroll
          for (int r = 0; r < 4; ++r) {
            float v = acc5[mi][nt][r] + b5f[nt] + bf2f(yb[(pxb + r)*72 + c]);
            afragF[(pxb + r)*33 + (c - chalf*32)] = v;
          }
        }
      }
      // own-wave rows: thread tid reads row tid (written by its own wave) — no barrier needed
      #pragma unroll 4
      for (int cc = 0; cc < 32; ++cc)
        op[(size_t)(chalf*32 + cc) * HW + tid] = afragF[tid*33 + cc];
    }
  }
}

extern "C" void kernel_launch(void* const* d_in, const int* in_sizes, int n_in,
                              void* d_out, int out_size, void* d_ws, size_t ws_size,
                              hipStream_t stream) {
  const float* inp   = (const float*)d_in[0];
  const float* probs = (const float*)d_in[1];
  const float* ln1w  = (const float*)d_in[2];
  const float* ln1b  = (const float*)d_in[3];
  const float* ln2w  = (const float*)d_in[4];
  const float* ln2b  = (const float*)d_in[5];
  const float* w1    = (const float*)d_in[6];
  const float* b1    = (const float*)d_in[7];
  const float* la1   = (const float*)d_in[8];
  const float* lb1   = (const float*)d_in[9];
  const float* w2    = (const float*)d_in[10];
  const float* b2    = (const float*)d_in[11];
  const float* la2   = (const float*)d_in[12];
  const float* lb2   = (const float*)d_in[13];
  const float* wsca  = (const float*)d_in[14];
  const float* bsca  = (const float*)d_in[15];
  const float* lasca = (const float*)d_in[16];
  const float* lbsca = (const float*)d_in[17];
  const float* w3    = (const float*)d_in[18];
  const float* b3    = (const float*)d_in[19];
  const float* la3   = (const float*)d_in[20];
  const float* lb3   = (const float*)d_in[21];
  const float* w4    = (const float*)d_in[22];
  const float* b4    = (const float*)d_in[23];
  const float* la4   = (const float*)d_in[24];
  const float* lb4   = (const float*)d_in[25];
  const float* w5    = (const float*)d_in[26];
  const float* b5    = (const float*)d_in[27];
  const float* la5   = (const float*)d_in[28];
  const float* lb5   = (const float*)d_in[29];
  const float* beta  = (const float*)d_in[30];
  const float* gamma = (const float*)d_in[31];

  char* wsb = (char*)d_ws;
  float* weff   = (float*)(wsb + WEFF_OFF);
  U16*   fragw  = (U16*)(wsb + FRAG_OFF);
  float* pooled = (float*)(wsb + POOL_OFF);
  U16*   zws    = (U16*)(wsb + Z_OFF);
  float* outp   = (float*)d_out;

  k_weights<<<dim3(24), dim3(256), 0, stream>>>(probs,
      w1, la1, lb1, w2, la2, lb2, wsca, lasca, lbsca,
      w3, la3, lb3, w4, la4, lb4, w5, la5, lb5,
      b3, b5, beta, gamma, ln1w, ln1b, b1, weff, fragw, pooled);
  k_stage1f<<<dim3(2048), dim3(256), 0, stream>>>(inp, b2, weff, fragw, zws, pooled);
  k_stage2<<<dim3(1024), dim3(256), 0, stream>>>(inp, zws, bsca, pooled, ln2w, ln2b, b4, weff, fragw, outp);
}